// Round 10
// baseline (474.840 us; speedup 1.0000x reference)
//
#include <hip/hip_runtime.h>
#include <hip/hip_bf16.h>

#define D 128
#define EPSV 1e-5f
#define BSH 7
#define BWIDTH 128
#define NCB 256          // chunk blocks for bucket hist/fill
#define MAXBUCK 1024

typedef __attribute__((ext_vector_type(8))) short bf16x8;
typedef __attribute__((ext_vector_type(4))) float f32x4;
typedef unsigned short u16;

__device__ inline u16 f2bf(float f) {
    unsigned int u = __builtin_bit_cast(unsigned int, f);
    return (u16)((u + 0x7fffu + ((u >> 16) & 1u)) >> 16);
}
__device__ inline float bf2f(u16 u) {
    unsigned int x = ((unsigned int)u) << 16;
    return __builtin_bit_cast(float, x);
}

// ---------- f32 -> bf16 conversion ----------
__global__ void k_cvt(const float* __restrict__ in, u16* __restrict__ out, long long n8) {
    long long i = (long long)blockIdx.x * blockDim.x + threadIdx.x;
    long long stride = (long long)gridDim.x * blockDim.x;
    for (; i < n8; i += stride) {
        const float4 v0 = *(const float4*)(in + i * 8);
        const float4 v1 = *(const float4*)(in + i * 8 + 4);
        bf16x8 o;
        o[0] = (short)f2bf(v0.x); o[1] = (short)f2bf(v0.y);
        o[2] = (short)f2bf(v0.z); o[3] = (short)f2bf(v0.w);
        o[4] = (short)f2bf(v1.x); o[5] = (short)f2bf(v1.y);
        o[6] = (short)f2bf(v1.z); o[7] = (short)f2bf(v1.w);
        *(bf16x8*)(out + i * 8) = o;
    }
}

// ---------- 4 weight matrices f32->bf16 in one launch (each 128x128) ----------
__global__ __launch_bounds__(256) void k_cvt4(const float* __restrict__ s0, const float* __restrict__ s1,
                                              const float* __restrict__ s2, const float* __restrict__ s3,
                                              u16* __restrict__ out) {
    int i = blockIdx.x * 256 + threadIdx.x;
    int mat = i >> 11;
    int off = (i & 2047) * 8;
    const float* src = (mat == 0) ? s0 : (mat == 1) ? s1 : (mat == 2) ? s2 : s3;
    const float4 v0 = *(const float4*)(src + off);
    const float4 v1 = *(const float4*)(src + off + 4);
    bf16x8 o;
    o[0] = (short)f2bf(v0.x); o[1] = (short)f2bf(v0.y);
    o[2] = (short)f2bf(v0.z); o[3] = (short)f2bf(v0.w);
    o[4] = (short)f2bf(v1.x); o[5] = (short)f2bf(v1.y);
    o[6] = (short)f2bf(v1.z); o[7] = (short)f2bf(v1.w);
    *(bf16x8*)(out + (size_t)i * 8) = o;
}

// ---------- bucket histogram (LDS) ----------
__global__ __launch_bounds__(256) void k_bhist(const int* __restrict__ dst, int E, int chunk,
                                               int nbuck, int* __restrict__ bh) {
    __shared__ int h[MAXBUCK];
    int t = threadIdx.x;
    for (int i = t; i < nbuck; i += 256) h[i] = 0;
    __syncthreads();
    int beg = blockIdx.x * chunk, end = min(E, beg + chunk);
    for (int i = beg + t; i < end; i += 256) atomicAdd(&h[dst[i] >> BSH], 1);
    __syncthreads();
    for (int i = t; i < nbuck; i += 256) bh[(size_t)blockIdx.x * nbuck + i] = h[i];
}

// ---------- column scan ----------
__global__ __launch_bounds__(NCB) void k_colscan(int* __restrict__ bh, int nbuck, int* __restrict__ btot) {
    __shared__ int sm[NCB];
    int b = blockIdx.x;
    int t = threadIdx.x;
    int v = bh[(size_t)t * nbuck + b];
    sm[t] = v;
    __syncthreads();
    for (int off = 1; off < NCB; off <<= 1) {
        int a = (t >= off) ? sm[t - off] : 0;
        __syncthreads();
        sm[t] += a;
        __syncthreads();
    }
    bh[(size_t)t * nbuck + b] = sm[t] - v;
    if (t == NCB - 1) btot[b] = sm[t];
}

// ---------- bucket-total scan -> bbase ----------
__global__ __launch_bounds__(1024) void k_btotscan(const int* __restrict__ btot, int nbuck,
                                                   int* __restrict__ bbase, int* __restrict__ row_ptr,
                                                   int M, int E) {
    __shared__ int sm[1024];
    int t = threadIdx.x;
    int v = (t < nbuck) ? btot[t] : 0;
    sm[t] = v;
    __syncthreads();
    for (int off = 1; off < 1024; off <<= 1) {
        int a = (t >= off) ? sm[t - off] : 0;
        __syncthreads();
        sm[t] += a;
        __syncthreads();
    }
    if (t < nbuck) bbase[t] = sm[t] - v;
    if (t == 0) { bbase[nbuck] = E; row_ptr[M] = E; }
}

// ---------- bucket fill: pairs[pos] = (dstlow<<24) | src ----------
__global__ __launch_bounds__(256) void k_bfill(const int* __restrict__ src, const int* __restrict__ dst,
                                               int E, int chunk, int nbuck, const int* __restrict__ bh,
                                               const int* __restrict__ bbase, unsigned int* __restrict__ pairs) {
    __shared__ int cur[MAXBUCK];
    int t = threadIdx.x;
    for (int i = t; i < nbuck; i += 256)
        cur[i] = bbase[i] + bh[(size_t)blockIdx.x * nbuck + i];
    __syncthreads();
    int beg = blockIdx.x * chunk, end = min(E, beg + chunk);
    for (int i = beg + t; i < end; i += 256) {
        int d = dst[i];
        int bk = d >> BSH;
        int pos = atomicAdd(&cur[bk], 1);
        pairs[pos] = (unsigned int)src[i] | ((unsigned int)(d & (BWIDTH - 1)) << 24);
    }
}

// ---------- per-bucket: node histogram + scan -> row_ptr, csr ----------
__global__ __launch_bounds__(256) void k_b2csr(const unsigned int* __restrict__ pairs,
                                               const int* __restrict__ bbase, int nbuck, int M,
                                               int* __restrict__ row_ptr, int* __restrict__ csr) {
    __shared__ int nh[BWIDTH];
    __shared__ int sc[BWIDTH];
    __shared__ int nc[BWIDTH];
    int b = blockIdx.x;
    int t = threadIdx.x;
    int node0 = b << BSH;
    int beg = bbase[b], end = bbase[b + 1];
    if (t < BWIDTH) nh[t] = 0;
    __syncthreads();
    for (int i = beg + t; i < end; i += 256) atomicAdd(&nh[pairs[i] >> 24], 1);
    __syncthreads();
    if (t < BWIDTH) sc[t] = nh[t];
    __syncthreads();
    for (int off = 1; off < BWIDTH; off <<= 1) {
        int a = 0;
        if (t < BWIDTH && t >= off) a = sc[t - off];
        __syncthreads();
        if (t < BWIDTH) sc[t] += a;
        __syncthreads();
    }
    if (t < BWIDTH) {
        int ex = sc[t] - nh[t];
        nc[t] = ex;
        int node = node0 + t;
        if (node < M) row_ptr[node] = beg + ex;
    }
    __syncthreads();
    for (int i = beg + t; i < end; i += 256) {
        unsigned int p = pairs[i];
        int pos = atomicAdd(&nc[p >> 24], 1);
        csr[beg + pos] = (int)(p & 0xFFFFFFu);
    }
}

// ---------- gather-aggregate (bf16 rows): 16 lanes per node, 8-deep pipeline ----------
__global__ __launch_bounds__(256) void k_gather(const u16* __restrict__ feat, const int* __restrict__ rp,
                                                const int* __restrict__ csr, u16* __restrict__ msg, int M) {
    int sub = threadIdx.x & 15;
    int node = blockIdx.x * 16 + (threadIdx.x >> 4);
    if (node >= M) return;
    int beg = rp[node], end = rp[node + 1];
    float a0[8], a1[8], a2[8], a3[8];
    #pragma unroll
    for (int j = 0; j < 8; j++) { a0[j] = 0.f; a1[j] = 0.f; a2[j] = 0.f; a3[j] = 0.f; }
    int e = beg;
    for (; e + 7 < end; e += 8) {
        int s0 = csr[e], s1 = csr[e + 1], s2 = csr[e + 2], s3 = csr[e + 3];
        int s4 = csr[e + 4], s5 = csr[e + 5], s6 = csr[e + 6], s7 = csr[e + 7];
        bf16x8 v0 = *(const bf16x8*)(feat + (size_t)s0 * D + sub * 8);
        bf16x8 v1 = *(const bf16x8*)(feat + (size_t)s1 * D + sub * 8);
        bf16x8 v2 = *(const bf16x8*)(feat + (size_t)s2 * D + sub * 8);
        bf16x8 v3 = *(const bf16x8*)(feat + (size_t)s3 * D + sub * 8);
        bf16x8 v4 = *(const bf16x8*)(feat + (size_t)s4 * D + sub * 8);
        bf16x8 v5 = *(const bf16x8*)(feat + (size_t)s5 * D + sub * 8);
        bf16x8 v6 = *(const bf16x8*)(feat + (size_t)s6 * D + sub * 8);
        bf16x8 v7 = *(const bf16x8*)(feat + (size_t)s7 * D + sub * 8);
        #pragma unroll
        for (int j = 0; j < 8; j++) {
            a0[j] += bf2f((u16)v0[j]); a1[j] += bf2f((u16)v1[j]);
            a2[j] += bf2f((u16)v2[j]); a3[j] += bf2f((u16)v3[j]);
            a0[j] += bf2f((u16)v4[j]); a1[j] += bf2f((u16)v5[j]);
            a2[j] += bf2f((u16)v6[j]); a3[j] += bf2f((u16)v7[j]);
        }
    }
    for (; e + 3 < end; e += 4) {
        int s0 = csr[e], s1 = csr[e + 1], s2 = csr[e + 2], s3 = csr[e + 3];
        bf16x8 v0 = *(const bf16x8*)(feat + (size_t)s0 * D + sub * 8);
        bf16x8 v1 = *(const bf16x8*)(feat + (size_t)s1 * D + sub * 8);
        bf16x8 v2 = *(const bf16x8*)(feat + (size_t)s2 * D + sub * 8);
        bf16x8 v3 = *(const bf16x8*)(feat + (size_t)s3 * D + sub * 8);
        #pragma unroll
        for (int j = 0; j < 8; j++) {
            a0[j] += bf2f((u16)v0[j]); a1[j] += bf2f((u16)v1[j]);
            a2[j] += bf2f((u16)v2[j]); a3[j] += bf2f((u16)v3[j]);
        }
    }
    for (; e < end; e++) {
        bf16x8 v0 = *(const bf16x8*)(feat + (size_t)csr[e] * D + sub * 8);
        #pragma unroll
        for (int j = 0; j < 8; j++) a0[j] += bf2f((u16)v0[j]);
    }
    float inv = 1.0f / fmaxf((float)(end - beg), 1.0f);
    bf16x8 o;
    #pragma unroll
    for (int j = 0; j < 8; j++) o[j] = (short)f2bf((a0[j] + a1[j] + a2[j] + a3[j]) * inv);
    *(bf16x8*)(msg + (size_t)node * D + sub * 8) = o;
}

// ---- fused GEMM v5: pure register streaming. Block = 4 waves = one 64-row strip.
// Wave w owns column-tiles nt = 2w, 2w+1; W-fragments live in registers (loaded once,
// L2-hot). A-fragments loaded per 16-row m-tile; all 4 waves read identical A
// addresses -> L1 merge, HBM sees A once. No LDS, no barriers.
// C = act( A1 @ W1^T [+ A2 @ W2^T] + bias ); A,W bf16
template <int TWO, int RELU, int OUTBF>
__global__ __launch_bounds__(256) void k_gemm(
    const u16* __restrict__ A1, const u16* __restrict__ A2,
    const u16* __restrict__ W1b, const u16* __restrict__ W2b,
    const float* __restrict__ bias, void* __restrict__ Cout, int M) {
    constexpr int NOPS = TWO ? 2 : 1;
    int t = threadIdx.x;
    int lane = t & 63, wave = t >> 6;
    int rlo = lane & 15, khi = lane >> 4;
    int m0 = blockIdx.x * 64;

    // W fragments in registers: nt = 2*wave + j
    bf16x8 wf[NOPS][2][4];
    #pragma unroll
    for (int j = 0; j < 2; j++) {
        int wrow = (wave * 2 + j) * 16 + rlo;
        #pragma unroll
        for (int kk = 0; kk < 4; kk++) {
            wf[0][j][kk] = *(const bf16x8*)(W1b + (size_t)wrow * D + kk * 32 + khi * 8);
            if (TWO) wf[1][j][kk] = *(const bf16x8*)(W2b + (size_t)wrow * D + kk * 32 + khi * 8);
        }
    }
    float bn0 = bias[(wave * 2 + 0) * 16 + rlo];
    float bn1 = bias[(wave * 2 + 1) * 16 + rlo];

    #pragma unroll
    for (int mt = 0; mt < 4; mt++) {
        int ra = m0 + mt * 16 + rlo;
        if (ra > M - 1) ra = M - 1;
        bf16x8 af[NOPS][4];
        #pragma unroll
        for (int kk = 0; kk < 4; kk++) {
            af[0][kk] = *(const bf16x8*)(A1 + (size_t)ra * D + kk * 32 + khi * 8);
            if (TWO) af[1][kk] = *(const bf16x8*)(A2 + (size_t)ra * D + kk * 32 + khi * 8);
        }
        f32x4 acc0 = (f32x4){0.f, 0.f, 0.f, 0.f};
        f32x4 acc1 = (f32x4){0.f, 0.f, 0.f, 0.f};
        #pragma unroll
        for (int o = 0; o < NOPS; o++)
            #pragma unroll
            for (int kk = 0; kk < 4; kk++) {
                acc0 = __builtin_amdgcn_mfma_f32_16x16x32_bf16(af[o][kk], wf[o][0][kk], acc0, 0, 0, 0);
                acc1 = __builtin_amdgcn_mfma_f32_16x16x32_bf16(af[o][kk], wf[o][1][kk], acc1, 0, 0, 0);
            }
        // C/D: col = lane&15 (per nt), row = khi*4 + r
        int row0 = m0 + mt * 16 + khi * 4;
        #pragma unroll
        for (int j = 0; j < 2; j++) {
            int col = (wave * 2 + j) * 16 + rlo;
            float bn = j ? bn1 : bn0;
            f32x4 a = j ? acc1 : acc0;
            #pragma unroll
            for (int r = 0; r < 4; r++) {
                int row = row0 + r;
                if (row < M) {
                    float v = a[r] + bn;
                    if (RELU) v = fmaxf(v, 0.0f);
                    if (OUTBF) ((u16*)Cout)[(size_t)row * D + col] = f2bf(v);
                    else       ((float*)Cout)[(size_t)row * D + col] = v;
                }
            }
        }
    }
}

// ---------- batchnorm stats (bf16 input, LDS pre-reduce, few atomics) ----------
__global__ __launch_bounds__(256) void k_bnstats(const u16* __restrict__ h, int M, float* __restrict__ stats) {
    __shared__ float ssum[256];
    __shared__ float ssq[256];
    int col = threadIdx.x & 127;
    int half = threadIdx.x >> 7;
    float s = 0.f, s2 = 0.f;
    for (int r = blockIdx.x * 2 + half; r < M; r += 512) {
        float v = bf2f(h[(size_t)r * D + col]);
        s += v;
        s2 += v * v;
    }
    ssum[threadIdx.x] = s;
    ssq[threadIdx.x] = s2;
    __syncthreads();
    if (threadIdx.x < 128) {
        unsafeAtomicAdd(&stats[col], ssum[threadIdx.x] + ssum[threadIdx.x + 128]);
        unsafeAtomicAdd(&stats[128 + col], ssq[threadIdx.x] + ssq[threadIdx.x + 128]);
    }
}

// ---------- BN fold into fcW/fcb: one block per output row ----------
__global__ __launch_bounds__(128) void k_bnfold(const float* __restrict__ stats,
                                                const float* __restrict__ gamma, const float* __restrict__ beta,
                                                const float* __restrict__ fcW, const float* __restrict__ fcb,
                                                int M, u16* __restrict__ Wfold, float* __restrict__ bias2) {
    __shared__ float red[128];
    int n = blockIdx.x, t = threadIdx.x;
    float mu = stats[t] / (float)M;
    float var = stats[128 + t] / (float)M - mu * mu;
    float sc = gamma[t] * rsqrtf(var + EPSV);
    float sh = beta[t] - mu * sc;
    float w = fcW[(size_t)n * D + t];
    Wfold[(size_t)n * D + t] = f2bf(w * sc);
    red[t] = sh * w;
    __syncthreads();
    for (int off = 64; off > 0; off >>= 1) {
        if (t < off) red[t] += red[t + off];
        __syncthreads();
    }
    if (t == 0) bias2[n] = fcb[n] + red[0];
}

static inline size_t alup(size_t x) { return (x + 63) & ~(size_t)63; }

extern "C" void kernel_launch(void* const* d_in, const int* in_sizes, int n_in,
                              void* d_out, int out_size, void* d_ws, size_t ws_size,
                              hipStream_t stream) {
    const float* x   = (const float*)d_in[0];
    const int*   ei  = (const int*)d_in[1];
    const float* Wl1 = (const float*)d_in[2];
    const float* bl1 = (const float*)d_in[3];
    const float* Wr1 = (const float*)d_in[4];
    const float* Wl2 = (const float*)d_in[5];
    const float* bl2 = (const float*)d_in[6];
    const float* Wr2 = (const float*)d_in[7];
    const float* gamma = (const float*)d_in[8];
    const float* beta  = (const float*)d_in[9];
    const float* fcW = (const float*)d_in[10];
    const float* fcb = (const float*)d_in[11];
    float* out = (float*)d_out;

    const int M = in_sizes[0] / D;
    const int E = in_sizes[1] / 2;
    const int* srcI = ei;
    const int* dstI = ei + E;
    const int nbuck = (M + BWIDTH - 1) >> BSH;
    const int chunk = (E + NCB - 1) / NCB;

    char* p = (char*)d_ws;
    u16* xb   = (u16*)p;            p += alup((size_t)M * D * 2);
    u16* msgb = (u16*)p;            p += alup((size_t)M * D * 2);
    u16* h1b  = (u16*)p;            p += alup((size_t)M * D * 2);
    u16* h2b  = (u16*)p;            p += alup((size_t)M * D * 2);
    unsigned int* pairs = (unsigned int*)p; p += alup((size_t)E * 4);
    int* csr  = (int*)p;            p += alup((size_t)E * 4);
    int* row_ptr = (int*)p;         p += alup((size_t)(M + 1) * 4);
    int* bh   = (int*)p;            p += alup((size_t)NCB * nbuck * 4);
    int* btot = (int*)p;            p += alup((size_t)nbuck * 4);
    int* bbase= (int*)p;            p += alup((size_t)(nbuck + 1) * 4);
    float* stats = (float*)p;       p += alup(256 * 4);
    u16* Wb   = (u16*)p;            p += alup((size_t)4 * D * D * 2);   // Wl1|Wr1|Wl2|Wr2
    u16* Wfoldb = (u16*)p;          p += alup((size_t)D * D * 2);
    float* bias2 = (float*)p;       p += alup(128 * 4);

    u16* Wl1b = Wb;
    u16* Wr1b = Wb + 16384;
    u16* Wl2b = Wb + 32768;
    u16* Wr2b = Wb + 49152;

    const int gemm_grid = (M + 63) / 64;
    const int gather_grid = (M + 15) / 16;

    hipMemsetAsync(stats, 0, 256 * sizeof(float), stream);

    // conversions + CSR build
    k_cvt<<<2048, 256, 0, stream>>>(x, xb, (long long)M * D / 8);
    k_cvt4<<<32, 256, 0, stream>>>(Wl1, Wr1, Wl2, Wr2, Wb);
    k_bhist<<<NCB, 256, 0, stream>>>(dstI, E, chunk, nbuck, bh);
    k_colscan<<<nbuck, NCB, 0, stream>>>(bh, nbuck, btot);
    k_btotscan<<<1, 1024, 0, stream>>>(btot, nbuck, bbase, row_ptr, M, E);
    k_bfill<<<NCB, 256, 0, stream>>>(srcI, dstI, E, chunk, nbuck, bh, bbase, pairs);
    k_b2csr<<<nbuck, 256, 0, stream>>>(pairs, bbase, nbuck, M, row_ptr, csr);

    // layer 1
    k_gather<<<gather_grid, 256, 0, stream>>>(xb, row_ptr, csr, msgb, M);
    k_gemm<1, 1, 1><<<gemm_grid, 256, 0, stream>>>(msgb, xb, Wl1b, Wr1b, bl1, h1b, M);

    // layer 2
    k_gather<<<gather_grid, 256, 0, stream>>>(h1b, row_ptr, csr, msgb, M);
    k_gemm<1, 1, 1><<<gemm_grid, 256, 0, stream>>>(msgb, h1b, Wl2b, Wr2b, bl2, h2b, M);

    // batchnorm stats + fold into fc weights
    k_bnstats<<<256, 256, 0, stream>>>(h2b, M, stats);
    k_bnfold<<<128, 128, 0, stream>>>(stats, gamma, beta, fcW, fcb, M, Wfoldb, bias2);

    // final fc (BN folded into Wfold/bias2)
    k_gemm<0, 0, 0><<<gemm_grid, 256, 0, stream>>>(h2b, nullptr, Wfoldb, nullptr, bias2, out, M);
}